// Round 10
// baseline (193.156 us; speedup 1.0000x reference)
//
#include <hip/hip_runtime.h>
#include <math.h>

#define N_NODES 100000
#define N_EDGES 1600000
#define C_IN    64
#define C_HID   32
#define LSTM_H  256
#define LSTM_IN 96
#define A_DIM   64

#define CAP     64                     // per-node bucket capacity (P(deg>64) ~ 1e-19)
#define RANGE   256                    // nodes per range
#define NRANGE  391                    // ceil(100000/256)
#define BCAP    32                     // LDS pairs per bin in k_part (mean 16/bin/block)
#define RCAP    4608                   // staged capacity per range (avg 4096 + 8 sigma)
#define PBLK    256                    // k_part blocks
#define EPB     (N_EDGES / PBLK)       // 6250 edges per k_part block

typedef unsigned int uint;
typedef float v2f __attribute__((ext_vector_type(2)));

// ---- fp8 e4m3 pack/unpack via HW converts (self-consistent roundtrip) ----
__device__ __forceinline__ uint pack4_fp8(float a, float b, float c, float d) {
    int u = 0;
    u = __builtin_amdgcn_cvt_pk_fp8_f32(a, b, u, false);
    u = __builtin_amdgcn_cvt_pk_fp8_f32(c, d, u, true);
    return (uint)u;
}
__device__ __forceinline__ void acc_fp8x8(uint2 r, float* a) {
    v2f f;
    f = __builtin_amdgcn_cvt_pk_f32_fp8(r.x, false); a[0] += f.x; a[1] += f.y;
    f = __builtin_amdgcn_cvt_pk_f32_fp8(r.x, true);  a[2] += f.x; a[3] += f.y;
    f = __builtin_amdgcn_cvt_pk_f32_fp8(r.y, false); a[4] += f.x; a[5] += f.y;
    f = __builtin_amdgcn_cvt_pk_f32_fp8(r.y, true);  a[6] += f.x; a[7] += f.y;
}

// ---------------- init: zero cursors + pooled + pad rows ----------------
__global__ __launch_bounds__(256) void k_init(int* __restrict__ gcur, float* __restrict__ pooled,
                                              uint* __restrict__ hs8, uint* __restrict__ hs2) {
    int tid = threadIdx.x;
    for (int i = tid; i < 512; i += 256) gcur[i] = 0;
    if (tid < C_HID) pooled[tid] = 0.0f;
    if (tid < 8) hs8[(size_t)N_NODES * 8 + tid] = 0u;   // zero pad row (dummy node)
    if (tid >= 8 && tid < 16) hs2[(size_t)N_NODES * 8 + tid - 8] = 0u;
}

// ---------------- phase 1: partition edges by 256-node range ----------------
// Per-edge cost: LDS atomic + LDS store. Global: coalesced chunk flushes,
// one cursor atomic per (block,bin). Packed entry: r | (c&255)<<24.
__global__ __launch_bounds__(256) void k_part(const int* __restrict__ row, const int* __restrict__ col,
                                              int* __restrict__ gcur, uint* __restrict__ staged) {
    __shared__ uint pairbuf[NRANGE][BCAP];
    __shared__ int bincnt[NRANGE];
    int tid = threadIdx.x;
    for (int i = tid; i < NRANGE; i += 256) bincnt[i] = 0;
    __syncthreads();
    int e0 = blockIdx.x * EPB;
    int e1 = min(e0 + EPB, N_EDGES);
    for (int e = e0 + tid; e < e1; e += 256) {
        int c = __builtin_nontemporal_load(col + e);
        int r = __builtin_nontemporal_load(row + e);
        int bin = c >> 8;
        uint pk = (uint)r | ((uint)(c & 255) << 24);
        int slot = atomicAdd(&bincnt[bin], 1);
        if (slot < BCAP) {
            pairbuf[bin][slot] = pk;
        } else {                                      // rare spill
            int gp = atomicAdd(&gcur[bin], 1);
            if (gp < RCAP) staged[(size_t)bin * RCAP + gp] = pk;
        }
    }
    __syncthreads();
    for (int b = tid; b < NRANGE; b += 256) {
        int cnt = min(bincnt[b], BCAP);
        if (cnt > 0) {
            int base = atomicAdd(&gcur[b], cnt);
            int m = min(cnt, RCAP - base);
            uint* dst = staged + (size_t)b * RCAP + base;
            for (int j = 0; j < m; ++j) dst[j] = pairbuf[b][j];
        }
    }
}

// ---------------- fused: staged -> padded bucket (LDS cursors) + layer-1 dense ----------------
// Block b owns nodes [b*256, b*256+256). Buckets padded to multiple of 16 with
// dummy index N_NODES (zero row) -> gather loop needs no predication.
__global__ __launch_bounds__(256) void k_bgcn(const int* __restrict__ gcur, const uint* __restrict__ staged,
                                              const float* __restrict__ x, const float* __restrict__ W1,
                                              int* __restrict__ cnt, int* __restrict__ nbr,
                                              uint* __restrict__ hs8) {
    __shared__ int cur[RANGE];
    __shared__ float sW[C_IN * C_HID];
    int tid = threadIdx.x, b = blockIdx.x;
    cur[tid] = 0;
    for (int i = tid; i < C_IN * C_HID; i += 256) sW[i] = W1[i];
    __syncthreads();
    int ce = min(gcur[b], RCAP);
    const uint* sbp = staged + (size_t)b * RCAP;
    for (int i = tid; i < ce; i += 256) {
        uint pk = sbp[i];
        int r = pk & 0xFFFFFF;
        int n = pk >> 24;
        int slot = atomicAdd(&cur[n], 1);
        if (slot < CAP) nbr[(size_t)(b * RANGE + n) * CAP + slot] = r;
    }
    __syncthreads();
    int v = b * RANGE + tid;
    if (v >= N_NODES) return;                    // no __syncthreads below
    int deg = min(cur[tid], CAP);
    int padded = min((deg + 15) & ~15, CAP);
    int* myb = nbr + (size_t)v * CAP;
    for (int s = deg; s < padded; ++s) myb[s] = N_NODES;   // dummy -> zero row
    cnt[v] = deg;
    // ---- layer-1 dense: hs8 = fp8((x @ W1) * dinv) ----
    float acc[C_HID];
#pragma unroll
    for (int c = 0; c < C_HID; ++c) acc[c] = 0.f;
    const float* xr = x + (size_t)v * C_IN;
#pragma unroll
    for (int k = 0; k < C_IN; k += 4) {
        float4 xv = *(const float4*)(xr + k);
#pragma unroll
        for (int c = 0; c < C_HID; ++c) {
            acc[c] = fmaf(xv.x, sW[(k + 0) * C_HID + c], acc[c]);
            acc[c] = fmaf(xv.y, sW[(k + 1) * C_HID + c], acc[c]);
            acc[c] = fmaf(xv.z, sW[(k + 2) * C_HID + c], acc[c]);
            acc[c] = fmaf(xv.w, sW[(k + 3) * C_HID + c], acc[c]);
        }
    }
    float dv = rsqrtf(1.0f + (float)deg);
    uint p[8];
#pragma unroll
    for (int c = 0; c < C_HID; c += 4)
        p[c >> 2] = pack4_fp8(acc[c] * dv, acc[c + 1] * dv, acc[c + 2] * dv, acc[c + 3] * dv);
    uint* hr = hs8 + (size_t)v * 8;
    *(uint4*)(hr + 0) = make_uint4(p[0], p[1], p[2], p[3]);
    *(uint4*)(hr + 4) = make_uint4(p[4], p[5], p[6], p[7]);
}

// Unconditional 16-deep gather over padded bucket, 4-lane groups.
// One uint4 idx load per lane per chunk; dummy rows are a zeroed hot line.
__device__ __forceinline__ void gather16p(const uint* __restrict__ tab, const int* __restrict__ nbrv,
                                          int padded, int l4, int gb4, float* acc) {
    for (int base = 0; base < padded; base += 16) {
        uint4 nv = *(const uint4*)(nbrv + base + l4 * 4);
        int nb[16];
#pragma unroll
        for (int j = 0; j < 16; ++j) {
            int c = (j & 3) == 0 ? (int)nv.x : (j & 3) == 1 ? (int)nv.y
                  : (j & 3) == 2 ? (int)nv.z : (int)nv.w;
            nb[j] = __shfl(c, gb4 + (j >> 2));
        }
        uint2 raw[16];
#pragma unroll
        for (int j = 0; j < 16; ++j)
            raw[j] = *(const uint2*)(tab + (size_t)nb[j] * 8 + l4 * 2);
#pragma unroll
        for (int j = 0; j < 16; ++j) acc_fp8x8(raw[j], acc);
    }
}

// ---------------- gather1 + finish1 + W2 GEMM ----------------
__global__ __launch_bounds__(256) void k_g1(const uint* __restrict__ hs8, const int* __restrict__ cnt,
                                            const int* __restrict__ nbr, const float* __restrict__ b1,
                                            const float* __restrict__ W2, uint* __restrict__ hs2) {
    __shared__ float sW[C_HID * C_HID];
    __shared__ float sx[64][C_HID + 1];
    int tid = threadIdx.x;
    for (int i = tid; i < C_HID * C_HID; i += 256) sW[i] = W2[i];
    int nl = tid >> 2, l4 = tid & 3, gb4 = (tid & 63) & ~3;
    int v = blockIdx.x * 64 + nl;
    float dv = 0.f;
    if (v < N_NODES) {
        float acc[8];
#pragma unroll
        for (int i = 0; i < 8; ++i) acc[i] = 0.f;
        uint2 selfr = *(const uint2*)(hs8 + (size_t)v * 8 + l4 * 2);
        acc_fp8x8(selfr, acc);
        int deg = cnt[v];
        int padded = min((deg + 15) & ~15, CAP);
        gather16p(hs8, nbr + (size_t)v * CAP, padded, l4, gb4, acc);
        dv = rsqrtf(1.0f + (float)deg);
#pragma unroll
        for (int i = 0; i < 8; ++i)
            sx[nl][l4 * 8 + i] = fmaxf(fmaf(acc[i], dv, b1[l4 * 8 + i]), 0.f);
    } else {
#pragma unroll
        for (int i = 0; i < 8; ++i) sx[nl][l4 * 8 + i] = 0.f;
    }
    __syncthreads();
    float o[8];
#pragma unroll
    for (int i = 0; i < 8; ++i) o[i] = 0.f;
#pragma unroll
    for (int k = 0; k < C_HID; ++k) {
        float xv = sx[nl][k];
#pragma unroll
        for (int i = 0; i < 8; ++i) o[i] = fmaf(xv, sW[k * C_HID + l4 * 8 + i], o[i]);
    }
    if (v < N_NODES) {
        uint2 wo;
        wo.x = pack4_fp8(o[0] * dv, o[1] * dv, o[2] * dv, o[3] * dv);
        wo.y = pack4_fp8(o[4] * dv, o[5] * dv, o[6] * dv, o[7] * dv);
        *(uint2*)(hs2 + (size_t)v * 8 + l4 * 2) = wo;
    }
}

// ---------------- gather2 + finish2 + mean-pool accumulate ----------------
__global__ __launch_bounds__(256) void k_g2(const uint* __restrict__ hs2, const int* __restrict__ cnt,
                                            const int* __restrict__ nbr, const float* __restrict__ b2,
                                            float* __restrict__ pooled) {
    __shared__ float sacc[4][C_HID];
    int tid = threadIdx.x;
    int nl = tid >> 2, l4 = tid & 3, gb4 = (tid & 63) & ~3, wid = tid >> 6;
    int v = blockIdx.x * 64 + nl;
    float x2[8];
#pragma unroll
    for (int i = 0; i < 8; ++i) x2[i] = 0.f;
    if (v < N_NODES) {
        float acc[8];
#pragma unroll
        for (int i = 0; i < 8; ++i) acc[i] = 0.f;
        uint2 selfr = *(const uint2*)(hs2 + (size_t)v * 8 + l4 * 2);
        acc_fp8x8(selfr, acc);
        int deg = cnt[v];
        int padded = min((deg + 15) & ~15, CAP);
        gather16p(hs2, nbr + (size_t)v * CAP, padded, l4, gb4, acc);
        float dv = rsqrtf(1.0f + (float)deg);
#pragma unroll
        for (int i = 0; i < 8; ++i)
            x2[i] = fmaxf(fmaf(acc[i], dv, b2[l4 * 8 + i]), 0.f);
    }
#pragma unroll
    for (int offd = 4; offd < 64; offd <<= 1) {
#pragma unroll
        for (int i = 0; i < 8; ++i) x2[i] += __shfl_down(x2[i], offd);
    }
    if ((tid & 63) < 4) {
#pragma unroll
        for (int i = 0; i < 8; ++i) sacc[wid][l4 * 8 + i] = x2[i];
    }
    __syncthreads();
    if (tid < C_HID) {
        float s = sacc[0][tid] + sacc[1][tid] + sacc[2][tid] + sacc[3][tid];
        unsafeAtomicAdd(&pooled[tid], s);
    }
}

// ---------------- LSTM gates GEMV (256 blocks, 4 rows each) ----------------
__global__ __launch_bounds__(256) void k_gates(const float* __restrict__ pooled, const float* __restrict__ x_state,
                                               const float* __restrict__ h0,
                                               const float* __restrict__ W_ih, const float* __restrict__ W_hh,
                                               const float* __restrict__ b_ih, const float* __restrict__ b_hh,
                                               float* __restrict__ gates) {
    __shared__ float sx[LSTM_IN + LSTM_H];
    int tid = threadIdx.x;
    for (int i = tid; i < LSTM_IN + LSTM_H; i += 256) {
        float v;
        if (i < C_HID)        v = pooled[i] * (1.0f / N_NODES);
        else if (i < LSTM_IN) v = x_state[i - C_HID];
        else                  v = h0[i - LSTM_IN];
        sx[i] = v;
    }
    __syncthreads();
    int wave = tid >> 6, lane = tid & 63;
    int r = blockIdx.x * 4 + wave;
    float p = 0.f;
    const float* wi = W_ih + (size_t)r * LSTM_IN;
    for (int k = lane; k < LSTM_IN; k += 64) p = fmaf(wi[k], sx[k], p);
    const float* wh = W_hh + (size_t)r * LSTM_H;
    for (int k = lane; k < LSTM_H; k += 64) p = fmaf(wh[k], sx[LSTM_IN + k], p);
#pragma unroll
    for (int off = 32; off; off >>= 1) p += __shfl_down(p, off);
    if (lane == 0) gates[r] = p + b_ih[r] + b_hh[r];
}

// ---------------- LSTM cell + FC head + log_softmax ----------------
__global__ __launch_bounds__(256) void k_head(const float* __restrict__ gates, const float* __restrict__ c0,
                                              const float* __restrict__ W_fc, const float* __restrict__ b_fc,
                                              float* __restrict__ out) {
    __shared__ float sh[LSTM_H];
    __shared__ float red[256];
    int t = threadIdx.x;
    float gi = gates[t], gf = gates[LSTM_H + t], gg = gates[2 * LSTM_H + t], go = gates[3 * LSTM_H + t];
    float i = 1.f / (1.f + expf(-gi));
    float f = 1.f / (1.f + expf(-gf));
    float g = tanhf(gg);
    float o = 1.f / (1.f + expf(-go));
    float c = fmaf(f, c0[t], i * g);
    float h = o * tanhf(c);
    out[A_DIM + t] = h;
    out[A_DIM + LSTM_H + t] = c;
    sh[t] = h;
    __syncthreads();
    int a = t & 63, part = t >> 6;
    float p = 0.f;
    for (int k = part * 64; k < part * 64 + 64; ++k) p = fmaf(sh[k], W_fc[k * A_DIM + a], p);
    red[t] = p;
    __syncthreads();
    if (t < 64) {
        float logit = red[t] + red[t + 64] + red[t + 128] + red[t + 192] + b_fc[t];
        float m = logit;
#pragma unroll
        for (int off = 32; off; off >>= 1) m = fmaxf(m, __shfl_xor(m, off));
        float e = expf(logit - m);
        float s = e;
#pragma unroll
        for (int off = 32; off; off >>= 1) s += __shfl_xor(s, off);
        out[t] = logit - m - logf(s);
    }
}

extern "C" void kernel_launch(void* const* d_in, const int* in_sizes, int n_in,
                              void* d_out, int out_size, void* d_ws, size_t ws_size,
                              hipStream_t stream) {
    const float* x_graph = (const float*)d_in[0];
    const int*   edge    = (const int*)d_in[1];
    const int*   row     = edge;
    const int*   col     = edge + N_EDGES;
    const float* x_state = (const float*)d_in[2];
    const float* h0      = (const float*)d_in[3];
    const float* c0      = (const float*)d_in[4];
    const float* W1      = (const float*)d_in[5];
    const float* b1      = (const float*)d_in[6];
    const float* W2      = (const float*)d_in[7];
    const float* b2      = (const float*)d_in[8];
    const float* W_ih    = (const float*)d_in[9];
    const float* W_hh    = (const float*)d_in[10];
    const float* b_ih    = (const float*)d_in[11];
    const float* b_hh    = (const float*)d_in[12];
    const float* W_fc    = (const float*)d_in[13];
    const float* b_fc    = (const float*)d_in[14];

    int*   gcur   = (int*)d_ws;                                  // 512
    uint*  staged = (uint*)(gcur + 512);                         // NRANGE*RCAP (7.2 MB)
    int*   cnt    = (int*)(staged + (size_t)NRANGE * RCAP);      // N
    int*   nbr    = cnt + N_NODES;                               // N*CAP (25.6 MB)
    uint*  hs8    = (uint*)(nbr + (size_t)N_NODES * CAP);        // (N+1)*8 (fp8 rows + pad row)
    uint*  hs2    = hs8 + (size_t)(N_NODES + 1) * 8;             // (N+1)*8
    float* pooled = (float*)(hs2 + (size_t)(N_NODES + 1) * 8);   // 32
    float* gates  = pooled + C_HID;                              // 1024
    float* out    = (float*)d_out;

    int nb_g = (N_NODES + 63) / 64;                              // 1563

    k_init  <<<1, 256, 0, stream>>>(gcur, pooled, hs8, hs2);
    k_part  <<<PBLK, 256, 0, stream>>>(row, col, gcur, staged);
    k_bgcn  <<<NRANGE, 256, 0, stream>>>(gcur, staged, x_graph, W1, cnt, nbr, hs8);
    k_g1    <<<nb_g, 256, 0, stream>>>(hs8, cnt, nbr, b1, W2, hs2);
    k_g2    <<<nb_g, 256, 0, stream>>>(hs2, cnt, nbr, b2, pooled);
    k_gates <<<256, 256, 0, stream>>>(pooled, x_state, h0, W_ih, W_hh, b_ih, b_hh, gates);
    k_head  <<<1, 256, 0, stream>>>(gates, c0, W_fc, b_fc, out);
}

// Round 11
// 191.878 us; speedup vs baseline: 1.0067x; 1.0067x over previous
//
#include <hip/hip_runtime.h>
#include <math.h>

#define N_NODES 100000
#define N_EDGES 1600000
#define C_IN    64
#define C_HID   32
#define LSTM_H  256
#define LSTM_IN 96
#define A_DIM   64

#define CAP     64                     // per-node bucket capacity (P(deg>64) ~ 1e-19)
#define RANGE   256                    // nodes per range
#define NRANGE  391                    // ceil(100000/256)
#define BCAP    32                     // LDS pairs per bin in k_part (mean 16/bin/block)
#define RCAP    4608                   // staged capacity per range (avg 4096 + 8 sigma)
#define PBLK    256                    // k_part blocks
#define EPB     (N_EDGES / PBLK)       // 6250 edges per k_part block

typedef unsigned int uint;
typedef float v2f __attribute__((ext_vector_type(2)));

// ---- fp8 e4m3 pack/unpack via HW converts (self-consistent roundtrip) ----
__device__ __forceinline__ uint pack4_fp8(float a, float b, float c, float d) {
    int u = 0;
    u = __builtin_amdgcn_cvt_pk_fp8_f32(a, b, u, false);
    u = __builtin_amdgcn_cvt_pk_fp8_f32(c, d, u, true);
    return (uint)u;
}
__device__ __forceinline__ void acc_fp8x8(uint2 r, float* a) {
    v2f f;
    f = __builtin_amdgcn_cvt_pk_f32_fp8(r.x, false); a[0] += f.x; a[1] += f.y;
    f = __builtin_amdgcn_cvt_pk_f32_fp8(r.x, true);  a[2] += f.x; a[3] += f.y;
    f = __builtin_amdgcn_cvt_pk_f32_fp8(r.y, false); a[4] += f.x; a[5] += f.y;
    f = __builtin_amdgcn_cvt_pk_f32_fp8(r.y, true);  a[6] += f.x; a[7] += f.y;
}

// ---------------- init: zero cursors + pooled + pad rows ----------------
__global__ __launch_bounds__(256) void k_init(int* __restrict__ gcur, float* __restrict__ pooled,
                                              uint* __restrict__ hs8, uint* __restrict__ hs2) {
    int tid = threadIdx.x;
    for (int i = tid; i < 512; i += 256) gcur[i] = 0;
    if (tid < C_HID) pooled[tid] = 0.0f;
    if (tid < 8) hs8[(size_t)N_NODES * 8 + tid] = 0u;   // zero pad row (dummy node)
    if (tid >= 8 && tid < 16) hs2[(size_t)N_NODES * 8 + tid - 8] = 0u;
}

// ---------------- phase 1: partition edges by 256-node range ----------------
// Per-edge cost: LDS atomic + LDS store. Global: coalesced chunk flushes,
// one cursor atomic per (block,bin). Packed entry: r | (c&255)<<24.
__global__ __launch_bounds__(256) void k_part(const int* __restrict__ row, const int* __restrict__ col,
                                              int* __restrict__ gcur, uint* __restrict__ staged) {
    __shared__ uint pairbuf[NRANGE][BCAP];
    __shared__ int bincnt[NRANGE];
    int tid = threadIdx.x;
    for (int i = tid; i < NRANGE; i += 256) bincnt[i] = 0;
    __syncthreads();
    int e0 = blockIdx.x * EPB;
    int e1 = min(e0 + EPB, N_EDGES);
    for (int e = e0 + tid; e < e1; e += 256) {
        int c = __builtin_nontemporal_load(col + e);
        int r = __builtin_nontemporal_load(row + e);
        int bin = c >> 8;
        uint pk = (uint)r | ((uint)(c & 255) << 24);
        int slot = atomicAdd(&bincnt[bin], 1);
        if (slot < BCAP) {
            pairbuf[bin][slot] = pk;
        } else {                                      // rare spill
            int gp = atomicAdd(&gcur[bin], 1);
            if (gp < RCAP) staged[(size_t)bin * RCAP + gp] = pk;
        }
    }
    __syncthreads();
    for (int b = tid; b < NRANGE; b += 256) {
        int cnt = min(bincnt[b], BCAP);
        if (cnt > 0) {
            int base = atomicAdd(&gcur[b], cnt);
            int m = min(cnt, RCAP - base);
            uint* dst = staged + (size_t)b * RCAP + base;
            for (int j = 0; j < m; ++j) dst[j] = pairbuf[b][j];
        }
    }
}

// ---------------- fused: staged -> padded bucket (LDS cursors) + layer-1 dense ----------------
// Block b owns nodes [b*256, b*256+256). Buckets padded to multiple of 16 with
// dummy index N_NODES (zero row) -> gather loop needs no predication.
__global__ __launch_bounds__(256) void k_bgcn(const int* __restrict__ gcur, const uint* __restrict__ staged,
                                              const float* __restrict__ x, const float* __restrict__ W1,
                                              int* __restrict__ cnt, int* __restrict__ nbr,
                                              uint* __restrict__ hs8) {
    __shared__ int cur[RANGE];
    __shared__ float sW[C_IN * C_HID];
    int tid = threadIdx.x, b = blockIdx.x;
    cur[tid] = 0;
    for (int i = tid; i < C_IN * C_HID; i += 256) sW[i] = W1[i];
    __syncthreads();
    int ce = min(gcur[b], RCAP);
    const uint* sbp = staged + (size_t)b * RCAP;
    for (int i = tid; i < ce; i += 256) {
        uint pk = sbp[i];
        int r = pk & 0xFFFFFF;
        int n = pk >> 24;
        int slot = atomicAdd(&cur[n], 1);
        if (slot < CAP) nbr[(size_t)(b * RANGE + n) * CAP + slot] = r;
    }
    __syncthreads();
    int v = b * RANGE + tid;
    if (v >= N_NODES) return;                    // no __syncthreads below
    int deg = min(cur[tid], CAP);
    int padded = min((deg + 15) & ~15, CAP);
    int* myb = nbr + (size_t)v * CAP;
    for (int s = deg; s < padded; ++s) myb[s] = N_NODES;   // dummy -> zero row
    cnt[v] = deg;
    // ---- layer-1 dense: hs8 = fp8((x @ W1) * dinv) ----
    float acc[C_HID];
#pragma unroll
    for (int c = 0; c < C_HID; ++c) acc[c] = 0.f;
    const float* xr = x + (size_t)v * C_IN;
#pragma unroll
    for (int k = 0; k < C_IN; k += 4) {
        float4 xv = *(const float4*)(xr + k);
#pragma unroll
        for (int c = 0; c < C_HID; ++c) {
            acc[c] = fmaf(xv.x, sW[(k + 0) * C_HID + c], acc[c]);
            acc[c] = fmaf(xv.y, sW[(k + 1) * C_HID + c], acc[c]);
            acc[c] = fmaf(xv.z, sW[(k + 2) * C_HID + c], acc[c]);
            acc[c] = fmaf(xv.w, sW[(k + 3) * C_HID + c], acc[c]);
        }
    }
    float dv = rsqrtf(1.0f + (float)deg);
    uint p[8];
#pragma unroll
    for (int c = 0; c < C_HID; c += 4)
        p[c >> 2] = pack4_fp8(acc[c] * dv, acc[c + 1] * dv, acc[c + 2] * dv, acc[c + 3] * dv);
    uint* hr = hs8 + (size_t)v * 8;
    *(uint4*)(hr + 0) = make_uint4(p[0], p[1], p[2], p[3]);
    *(uint4*)(hr + 4) = make_uint4(p[4], p[5], p[6], p[7]);
}

// Unconditional 16-deep gather over padded bucket, 4-lane groups.
// One uint4 idx load per lane per chunk; dummy rows are a zeroed hot line.
__device__ __forceinline__ void gather16p(const uint* __restrict__ tab, const int* __restrict__ nbrv,
                                          int padded, int l4, int gb4, float* acc) {
    for (int base = 0; base < padded; base += 16) {
        uint4 nv = *(const uint4*)(nbrv + base + l4 * 4);
        int nb[16];
#pragma unroll
        for (int j = 0; j < 16; ++j) {
            int c = (j & 3) == 0 ? (int)nv.x : (j & 3) == 1 ? (int)nv.y
                  : (j & 3) == 2 ? (int)nv.z : (int)nv.w;
            nb[j] = __shfl(c, gb4 + (j >> 2));
        }
        uint2 raw[16];
#pragma unroll
        for (int j = 0; j < 16; ++j)
            raw[j] = *(const uint2*)(tab + (size_t)nb[j] * 8 + l4 * 2);
#pragma unroll
        for (int j = 0; j < 16; ++j) acc_fp8x8(raw[j], acc);
    }
}

// ---------------- gather1 + finish1 + W2 GEMM ----------------
__global__ __launch_bounds__(256) void k_g1(const uint* __restrict__ hs8, const int* __restrict__ cnt,
                                            const int* __restrict__ nbr, const float* __restrict__ b1,
                                            const float* __restrict__ W2, uint* __restrict__ hs2) {
    __shared__ float sW[C_HID * C_HID];
    __shared__ float sx[64][C_HID + 1];
    int tid = threadIdx.x;
    for (int i = tid; i < C_HID * C_HID; i += 256) sW[i] = W2[i];
    int nl = tid >> 2, l4 = tid & 3, gb4 = (tid & 63) & ~3;
    int v = blockIdx.x * 64 + nl;
    float dv = 0.f;
    if (v < N_NODES) {
        float acc[8];
#pragma unroll
        for (int i = 0; i < 8; ++i) acc[i] = 0.f;
        uint2 selfr = *(const uint2*)(hs8 + (size_t)v * 8 + l4 * 2);
        acc_fp8x8(selfr, acc);
        int deg = cnt[v];
        int padded = min((deg + 15) & ~15, CAP);
        gather16p(hs8, nbr + (size_t)v * CAP, padded, l4, gb4, acc);
        dv = rsqrtf(1.0f + (float)deg);
#pragma unroll
        for (int i = 0; i < 8; ++i)
            sx[nl][l4 * 8 + i] = fmaxf(fmaf(acc[i], dv, b1[l4 * 8 + i]), 0.f);
    } else {
#pragma unroll
        for (int i = 0; i < 8; ++i) sx[nl][l4 * 8 + i] = 0.f;
    }
    __syncthreads();
    float o[8];
#pragma unroll
    for (int i = 0; i < 8; ++i) o[i] = 0.f;
#pragma unroll
    for (int k = 0; k < C_HID; ++k) {
        float xv = sx[nl][k];
#pragma unroll
        for (int i = 0; i < 8; ++i) o[i] = fmaf(xv, sW[k * C_HID + l4 * 8 + i], o[i]);
    }
    if (v < N_NODES) {
        uint2 wo;
        wo.x = pack4_fp8(o[0] * dv, o[1] * dv, o[2] * dv, o[3] * dv);
        wo.y = pack4_fp8(o[4] * dv, o[5] * dv, o[6] * dv, o[7] * dv);
        *(uint2*)(hs2 + (size_t)v * 8 + l4 * 2) = wo;
    }
}

// ---------------- gather2 + finish2 + mean-pool accumulate ----------------
__global__ __launch_bounds__(256) void k_g2(const uint* __restrict__ hs2, const int* __restrict__ cnt,
                                            const int* __restrict__ nbr, const float* __restrict__ b2,
                                            float* __restrict__ pooled) {
    __shared__ float sacc[4][C_HID];
    int tid = threadIdx.x;
    int nl = tid >> 2, l4 = tid & 3, gb4 = (tid & 63) & ~3, wid = tid >> 6;
    int v = blockIdx.x * 64 + nl;
    float x2[8];
#pragma unroll
    for (int i = 0; i < 8; ++i) x2[i] = 0.f;
    if (v < N_NODES) {
        float acc[8];
#pragma unroll
        for (int i = 0; i < 8; ++i) acc[i] = 0.f;
        uint2 selfr = *(const uint2*)(hs2 + (size_t)v * 8 + l4 * 2);
        acc_fp8x8(selfr, acc);
        int deg = cnt[v];
        int padded = min((deg + 15) & ~15, CAP);
        gather16p(hs2, nbr + (size_t)v * CAP, padded, l4, gb4, acc);
        float dv = rsqrtf(1.0f + (float)deg);
#pragma unroll
        for (int i = 0; i < 8; ++i)
            x2[i] = fmaxf(fmaf(acc[i], dv, b2[l4 * 8 + i]), 0.f);
    }
#pragma unroll
    for (int offd = 4; offd < 64; offd <<= 1) {
#pragma unroll
        for (int i = 0; i < 8; ++i) x2[i] += __shfl_down(x2[i], offd);
    }
    if ((tid & 63) < 4) {
#pragma unroll
        for (int i = 0; i < 8; ++i) sacc[wid][l4 * 8 + i] = x2[i];
    }
    __syncthreads();
    if (tid < C_HID) {
        float s = sacc[0][tid] + sacc[1][tid] + sacc[2][tid] + sacc[3][tid];
        unsafeAtomicAdd(&pooled[tid], s);
    }
}

// ---------------- LSTM gates GEMV (256 blocks, 4 rows each) ----------------
__global__ __launch_bounds__(256) void k_gates(const float* __restrict__ pooled, const float* __restrict__ x_state,
                                               const float* __restrict__ h0,
                                               const float* __restrict__ W_ih, const float* __restrict__ W_hh,
                                               const float* __restrict__ b_ih, const float* __restrict__ b_hh,
                                               float* __restrict__ gates) {
    __shared__ float sx[LSTM_IN + LSTM_H];
    int tid = threadIdx.x;
    for (int i = tid; i < LSTM_IN + LSTM_H; i += 256) {
        float v;
        if (i < C_HID)        v = pooled[i] * (1.0f / N_NODES);
        else if (i < LSTM_IN) v = x_state[i - C_HID];
        else                  v = h0[i - LSTM_IN];
        sx[i] = v;
    }
    __syncthreads();
    int wave = tid >> 6, lane = tid & 63;
    int r = blockIdx.x * 4 + wave;
    float p = 0.f;
    const float* wi = W_ih + (size_t)r * LSTM_IN;
    for (int k = lane; k < LSTM_IN; k += 64) p = fmaf(wi[k], sx[k], p);
    const float* wh = W_hh + (size_t)r * LSTM_H;
    for (int k = lane; k < LSTM_H; k += 64) p = fmaf(wh[k], sx[LSTM_IN + k], p);
#pragma unroll
    for (int off = 32; off; off >>= 1) p += __shfl_down(p, off);
    if (lane == 0) gates[r] = p + b_ih[r] + b_hh[r];
}

// ---------------- LSTM cell + FC head + log_softmax ----------------
__global__ __launch_bounds__(256) void k_head(const float* __restrict__ gates, const float* __restrict__ c0,
                                              const float* __restrict__ W_fc, const float* __restrict__ b_fc,
                                              float* __restrict__ out) {
    __shared__ float sh[LSTM_H];
    __shared__ float red[256];
    int t = threadIdx.x;
    float gi = gates[t], gf = gates[LSTM_H + t], gg = gates[2 * LSTM_H + t], go = gates[3 * LSTM_H + t];
    float i = 1.f / (1.f + expf(-gi));
    float f = 1.f / (1.f + expf(-gf));
    float g = tanhf(gg);
    float o = 1.f / (1.f + expf(-go));
    float c = fmaf(f, c0[t], i * g);
    float h = o * tanhf(c);
    out[A_DIM + t] = h;
    out[A_DIM + LSTM_H + t] = c;
    sh[t] = h;
    __syncthreads();
    int a = t & 63, part = t >> 6;
    float p = 0.f;
    for (int k = part * 64; k < part * 64 + 64; ++k) p = fmaf(sh[k], W_fc[k * A_DIM + a], p);
    red[t] = p;
    __syncthreads();
    if (t < 64) {
        float logit = red[t] + red[t + 64] + red[t + 128] + red[t + 192] + b_fc[t];
        float m = logit;
#pragma unroll
        for (int off = 32; off; off >>= 1) m = fmaxf(m, __shfl_xor(m, off));
        float e = expf(logit - m);
        float s = e;
#pragma unroll
        for (int off = 32; off; off >>= 1) s += __shfl_xor(s, off);
        out[t] = logit - m - logf(s);
    }
}

extern "C" void kernel_launch(void* const* d_in, const int* in_sizes, int n_in,
                              void* d_out, int out_size, void* d_ws, size_t ws_size,
                              hipStream_t stream) {
    const float* x_graph = (const float*)d_in[0];
    const int*   edge    = (const int*)d_in[1];
    const int*   row     = edge;
    const int*   col     = edge + N_EDGES;
    const float* x_state = (const float*)d_in[2];
    const float* h0      = (const float*)d_in[3];
    const float* c0      = (const float*)d_in[4];
    const float* W1      = (const float*)d_in[5];
    const float* b1      = (const float*)d_in[6];
    const float* W2      = (const float*)d_in[7];
    const float* b2      = (const float*)d_in[8];
    const float* W_ih    = (const float*)d_in[9];
    const float* W_hh    = (const float*)d_in[10];
    const float* b_ih    = (const float*)d_in[11];
    const float* b_hh    = (const float*)d_in[12];
    const float* W_fc    = (const float*)d_in[13];
    const float* b_fc    = (const float*)d_in[14];

    int*   gcur   = (int*)d_ws;                                  // 512
    uint*  staged = (uint*)(gcur + 512);                         // NRANGE*RCAP (7.2 MB)
    int*   cnt    = (int*)(staged + (size_t)NRANGE * RCAP);      // N
    int*   nbr    = cnt + N_NODES;                               // N*CAP (25.6 MB)
    uint*  hs8    = (uint*)(nbr + (size_t)N_NODES * CAP);        // (N+1)*8 (fp8 rows + pad row)
    uint*  hs2    = hs8 + (size_t)(N_NODES + 1) * 8;             // (N+1)*8
    float* pooled = (float*)(hs2 + (size_t)(N_NODES + 1) * 8);   // 32
    float* gates  = pooled + C_HID;                              // 1024
    float* out    = (float*)d_out;

    int nb_g = (N_NODES + 63) / 64;                              // 1563

    k_init  <<<1, 256, 0, stream>>>(gcur, pooled, hs8, hs2);
    k_part  <<<PBLK, 256, 0, stream>>>(row, col, gcur, staged);
    k_bgcn  <<<NRANGE, 256, 0, stream>>>(gcur, staged, x_graph, W1, cnt, nbr, hs8);
    k_g1    <<<nb_g, 256, 0, stream>>>(hs8, cnt, nbr, b1, W2, hs2);
    k_g2    <<<nb_g, 256, 0, stream>>>(hs2, cnt, nbr, b2, pooled);
    k_gates <<<256, 256, 0, stream>>>(pooled, x_state, h0, W_ih, W_hh, b_ih, b_hh, gates);
    k_head  <<<1, 256, 0, stream>>>(gates, c0, W_fc, b_fc, out);
}

// Round 12
// 116.575 us; speedup vs baseline: 1.6569x; 1.6460x over previous
//
#include <hip/hip_runtime.h>
#include <math.h>

#define N_NODES 100000
#define N_EDGES 1600000
#define C_IN    64
#define C_HID   32
#define LSTM_H  256
#define LSTM_IN 96
#define A_DIM   64

#define CAP     64                     // per-node bucket capacity (P(deg>64) ~ 1e-19)
#define RANGE   256                    // nodes per range
#define NRANGE  391                    // ceil(100000/256)
#define BCAP    32                     // LDS pairs per bin in k_part (mean 16/bin/block)
#define RCAP    4608                   // staged capacity per range (avg 4096 + 8 sigma)
#define PBLK    256                    // k_part blocks
#define EPB     (N_EDGES / PBLK)       // 6250 edges per k_part block

typedef unsigned int uint;
typedef float v2f __attribute__((ext_vector_type(2)));

// ---- fp8 e4m3 pack/unpack via HW converts (self-consistent roundtrip) ----
__device__ __forceinline__ uint pack4_fp8(float a, float b, float c, float d) {
    int u = 0;
    u = __builtin_amdgcn_cvt_pk_fp8_f32(a, b, u, false);
    u = __builtin_amdgcn_cvt_pk_fp8_f32(c, d, u, true);
    return (uint)u;
}
__device__ __forceinline__ void acc_fp8x8(uint2 r, float* a) {
    v2f f;
    f = __builtin_amdgcn_cvt_pk_f32_fp8(r.x, false); a[0] += f.x; a[1] += f.y;
    f = __builtin_amdgcn_cvt_pk_f32_fp8(r.x, true);  a[2] += f.x; a[3] += f.y;
    f = __builtin_amdgcn_cvt_pk_f32_fp8(r.y, false); a[4] += f.x; a[5] += f.y;
    f = __builtin_amdgcn_cvt_pk_f32_fp8(r.y, true);  a[6] += f.x; a[7] += f.y;
}

// ---------------- phase 1: partition edges by 256-node range ----------------
// Per-edge cost: LDS atomic + LDS store. Global: coalesced chunk flushes,
// one cursor atomic per (block,bin). Packed entry: r | (c&255)<<24.
// Block 0 also zeroes `pooled` (consumed only by k_g2, launched later).
__global__ __launch_bounds__(256) void k_part(const int* __restrict__ row, const int* __restrict__ col,
                                              int* __restrict__ gcur, uint* __restrict__ staged,
                                              float* __restrict__ pooled) {
    __shared__ uint pairbuf[NRANGE][BCAP];
    __shared__ int bincnt[NRANGE];
    int tid = threadIdx.x;
    if (blockIdx.x == 0 && tid < C_HID) pooled[tid] = 0.0f;
    for (int i = tid; i < NRANGE; i += 256) bincnt[i] = 0;
    __syncthreads();
    int e0 = blockIdx.x * EPB;
    int e1 = min(e0 + EPB, N_EDGES);
    for (int e = e0 + tid; e < e1; e += 256) {
        int c = __builtin_nontemporal_load(col + e);
        int r = __builtin_nontemporal_load(row + e);
        int bin = c >> 8;
        uint pk = (uint)r | ((uint)(c & 255) << 24);
        int slot = atomicAdd(&bincnt[bin], 1);
        if (slot < BCAP) {
            pairbuf[bin][slot] = pk;
        } else {                                      // rare spill
            int gp = atomicAdd(&gcur[bin], 1);
            if (gp < RCAP) staged[(size_t)bin * RCAP + gp] = pk;
        }
    }
    __syncthreads();
    for (int b = tid; b < NRANGE; b += 256) {
        int cnt = min(bincnt[b], BCAP);
        if (cnt > 0) {
            int base = atomicAdd(&gcur[b], cnt);
            int m = min(cnt, RCAP - base);
            uint* dst = staged + (size_t)b * RCAP + base;
            for (int j = 0; j < m; ++j) dst[j] = pairbuf[b][j];
        }
    }
}

// ---------------- fused: staged -> padded bucket (LDS cursors) + layer-1 dense ----------------
// Block b owns nodes [b*256, b*256+256).
__global__ __launch_bounds__(256) void k_bgcn(const int* __restrict__ gcur, const uint* __restrict__ staged,
                                              const float* __restrict__ x, const float* __restrict__ W1,
                                              int* __restrict__ cnt, int* __restrict__ nbr,
                                              uint* __restrict__ hs8) {
    __shared__ int cur[RANGE];
    __shared__ float sW[C_IN * C_HID];
    int tid = threadIdx.x, b = blockIdx.x;
    cur[tid] = 0;
    for (int i = tid; i < C_IN * C_HID; i += 256) sW[i] = W1[i];
    __syncthreads();
    int ce = min(gcur[b], RCAP);
    const uint* sbp = staged + (size_t)b * RCAP;
    for (int i = tid; i < ce; i += 256) {
        uint pk = sbp[i];
        int r = pk & 0xFFFFFF;
        int n = pk >> 24;
        int slot = atomicAdd(&cur[n], 1);
        if (slot < CAP) nbr[(size_t)(b * RANGE + n) * CAP + slot] = r;
    }
    __syncthreads();
    int v = b * RANGE + tid;
    if (v >= N_NODES) return;                    // no __syncthreads below
    int deg = min(cur[tid], CAP);
    cnt[v] = deg;
    // ---- layer-1 dense: hs8 = fp8((x @ W1) * dinv) ----
    float acc[C_HID];
#pragma unroll
    for (int c = 0; c < C_HID; ++c) acc[c] = 0.f;
    const float* xr = x + (size_t)v * C_IN;
#pragma unroll
    for (int k = 0; k < C_IN; k += 4) {
        float4 xv = *(const float4*)(xr + k);
#pragma unroll
        for (int c = 0; c < C_HID; ++c) {
            acc[c] = fmaf(xv.x, sW[(k + 0) * C_HID + c], acc[c]);
            acc[c] = fmaf(xv.y, sW[(k + 1) * C_HID + c], acc[c]);
            acc[c] = fmaf(xv.z, sW[(k + 2) * C_HID + c], acc[c]);
            acc[c] = fmaf(xv.w, sW[(k + 3) * C_HID + c], acc[c]);
        }
    }
    float dv = rsqrtf(1.0f + (float)deg);
    uint p[8];
#pragma unroll
    for (int c = 0; c < C_HID; c += 4)
        p[c >> 2] = pack4_fp8(acc[c] * dv, acc[c + 1] * dv, acc[c + 2] * dv, acc[c + 3] * dv);
    uint* hr = hs8 + (size_t)v * 8;
    *(uint4*)(hr + 0) = make_uint4(p[0], p[1], p[2], p[3]);
    *(uint4*)(hr + 4) = make_uint4(p[4], p[5], p[6], p[7]);
}

// Two-phase 16-deep gather over padded bucket, 4-lane groups. (Round-9 form:
// clamp + predicated accumulate — predication forces the compiler to keep the
// 16-load batch live (VGPR ~64) -> full MLP. Do NOT "simplify" (r11: -68%).)
__device__ __forceinline__ void gather16(const uint* __restrict__ tab, const int* __restrict__ nbrv,
                                         int deg, int l4, int gb4, float* acc) {
    for (int base = 0; base < deg; base += 16) {
        int nv[4];
#pragma unroll
        for (int j = 0; j < 4; ++j) {
            int idx = base + (j << 2) + l4;
            nv[j] = nbrv[(idx < deg) ? idx : (deg - 1)];
        }
        int cnt = deg - base;
        int nb[16];
#pragma unroll
        for (int j = 0; j < 16; ++j) nb[j] = __shfl(nv[j >> 2], gb4 + (j & 3));
        uint2 raw[16];
#pragma unroll
        for (int j = 0; j < 16; ++j)
            raw[j] = *(const uint2*)(tab + (size_t)nb[j] * 8 + l4 * 2);
#pragma unroll
        for (int j = 0; j < 16; ++j)
            if (j < cnt) acc_fp8x8(raw[j], acc);
    }
}

// ---------------- gather1 + finish1 + W2 GEMM ----------------
__global__ __launch_bounds__(256) void k_g1(const uint* __restrict__ hs8, const int* __restrict__ cnt,
                                            const int* __restrict__ nbr, const float* __restrict__ b1,
                                            const float* __restrict__ W2, uint* __restrict__ hs2) {
    __shared__ float sW[C_HID * C_HID];
    __shared__ float sx[64][C_HID + 1];
    int tid = threadIdx.x;
    for (int i = tid; i < C_HID * C_HID; i += 256) sW[i] = W2[i];
    int nl = tid >> 2, l4 = tid & 3, gb4 = (tid & 63) & ~3;
    int v = blockIdx.x * 64 + nl;
    float dv = 0.f;
    if (v < N_NODES) {
        float acc[8];
#pragma unroll
        for (int i = 0; i < 8; ++i) acc[i] = 0.f;
        uint2 selfr = *(const uint2*)(hs8 + (size_t)v * 8 + l4 * 2);
        acc_fp8x8(selfr, acc);
        int deg = cnt[v];
        gather16(hs8, nbr + (size_t)v * CAP, deg, l4, gb4, acc);
        dv = rsqrtf(1.0f + (float)deg);
#pragma unroll
        for (int i = 0; i < 8; ++i)
            sx[nl][l4 * 8 + i] = fmaxf(fmaf(acc[i], dv, b1[l4 * 8 + i]), 0.f);
    } else {
#pragma unroll
        for (int i = 0; i < 8; ++i) sx[nl][l4 * 8 + i] = 0.f;
    }
    __syncthreads();
    float o[8];
#pragma unroll
    for (int i = 0; i < 8; ++i) o[i] = 0.f;
#pragma unroll
    for (int k = 0; k < C_HID; ++k) {
        float xv = sx[nl][k];
#pragma unroll
        for (int i = 0; i < 8; ++i) o[i] = fmaf(xv, sW[k * C_HID + l4 * 8 + i], o[i]);
    }
    if (v < N_NODES) {
        uint2 wo;
        wo.x = pack4_fp8(o[0] * dv, o[1] * dv, o[2] * dv, o[3] * dv);
        wo.y = pack4_fp8(o[4] * dv, o[5] * dv, o[6] * dv, o[7] * dv);
        *(uint2*)(hs2 + (size_t)v * 8 + l4 * 2) = wo;
    }
}

// ---------------- gather2 + finish2 + mean-pool accumulate ----------------
__global__ __launch_bounds__(256) void k_g2(const uint* __restrict__ hs2, const int* __restrict__ cnt,
                                            const int* __restrict__ nbr, const float* __restrict__ b2,
                                            float* __restrict__ pooled) {
    __shared__ float sacc[4][C_HID];
    int tid = threadIdx.x;
    int nl = tid >> 2, l4 = tid & 3, gb4 = (tid & 63) & ~3, wid = tid >> 6;
    int v = blockIdx.x * 64 + nl;
    float x2[8];
#pragma unroll
    for (int i = 0; i < 8; ++i) x2[i] = 0.f;
    if (v < N_NODES) {
        float acc[8];
#pragma unroll
        for (int i = 0; i < 8; ++i) acc[i] = 0.f;
        uint2 selfr = *(const uint2*)(hs2 + (size_t)v * 8 + l4 * 2);
        acc_fp8x8(selfr, acc);
        int deg = cnt[v];
        gather16(hs2, nbr + (size_t)v * CAP, deg, l4, gb4, acc);
        float dv = rsqrtf(1.0f + (float)deg);
#pragma unroll
        for (int i = 0; i < 8; ++i)
            x2[i] = fmaxf(fmaf(acc[i], dv, b2[l4 * 8 + i]), 0.f);
    }
#pragma unroll
    for (int offd = 4; offd < 64; offd <<= 1) {
#pragma unroll
        for (int i = 0; i < 8; ++i) x2[i] += __shfl_down(x2[i], offd);
    }
    if ((tid & 63) < 4) {
#pragma unroll
        for (int i = 0; i < 8; ++i) sacc[wid][l4 * 8 + i] = x2[i];
    }
    __syncthreads();
    if (tid < C_HID) {
        float s = sacc[0][tid] + sacc[1][tid] + sacc[2][tid] + sacc[3][tid];
        unsafeAtomicAdd(&pooled[tid], s);
    }
}

// ---------------- LSTM gates GEMV (256 blocks, 4 rows each) ----------------
__global__ __launch_bounds__(256) void k_gates(const float* __restrict__ pooled, const float* __restrict__ x_state,
                                               const float* __restrict__ h0,
                                               const float* __restrict__ W_ih, const float* __restrict__ W_hh,
                                               const float* __restrict__ b_ih, const float* __restrict__ b_hh,
                                               float* __restrict__ gates) {
    __shared__ float sx[LSTM_IN + LSTM_H];
    int tid = threadIdx.x;
    for (int i = tid; i < LSTM_IN + LSTM_H; i += 256) {
        float v;
        if (i < C_HID)        v = pooled[i] * (1.0f / N_NODES);
        else if (i < LSTM_IN) v = x_state[i - C_HID];
        else                  v = h0[i - LSTM_IN];
        sx[i] = v;
    }
    __syncthreads();
    int wave = tid >> 6, lane = tid & 63;
    int r = blockIdx.x * 4 + wave;
    float p = 0.f;
    const float* wi = W_ih + (size_t)r * LSTM_IN;
    for (int k = lane; k < LSTM_IN; k += 64) p = fmaf(wi[k], sx[k], p);
    const float* wh = W_hh + (size_t)r * LSTM_H;
    for (int k = lane; k < LSTM_H; k += 64) p = fmaf(wh[k], sx[LSTM_IN + k], p);
#pragma unroll
    for (int off = 32; off; off >>= 1) p += __shfl_down(p, off);
    if (lane == 0) gates[r] = p + b_ih[r] + b_hh[r];
}

// ---------------- LSTM cell + FC head + log_softmax ----------------
__global__ __launch_bounds__(256) void k_head(const float* __restrict__ gates, const float* __restrict__ c0,
                                              const float* __restrict__ W_fc, const float* __restrict__ b_fc,
                                              float* __restrict__ out) {
    __shared__ float sh[LSTM_H];
    __shared__ float red[256];
    int t = threadIdx.x;
    float gi = gates[t], gf = gates[LSTM_H + t], gg = gates[2 * LSTM_H + t], go = gates[3 * LSTM_H + t];
    float i = 1.f / (1.f + expf(-gi));
    float f = 1.f / (1.f + expf(-gf));
    float g = tanhf(gg);
    float o = 1.f / (1.f + expf(-go));
    float c = fmaf(f, c0[t], i * g);
    float h = o * tanhf(c);
    out[A_DIM + t] = h;
    out[A_DIM + LSTM_H + t] = c;
    sh[t] = h;
    __syncthreads();
    int a = t & 63, part = t >> 6;
    float p = 0.f;
    for (int k = part * 64; k < part * 64 + 64; ++k) p = fmaf(sh[k], W_fc[k * A_DIM + a], p);
    red[t] = p;
    __syncthreads();
    if (t < 64) {
        float logit = red[t] + red[t + 64] + red[t + 128] + red[t + 192] + b_fc[t];
        float m = logit;
#pragma unroll
        for (int off = 32; off; off >>= 1) m = fmaxf(m, __shfl_xor(m, off));
        float e = expf(logit - m);
        float s = e;
#pragma unroll
        for (int off = 32; off; off >>= 1) s += __shfl_xor(s, off);
        out[t] = logit - m - logf(s);
    }
}

extern "C" void kernel_launch(void* const* d_in, const int* in_sizes, int n_in,
                              void* d_out, int out_size, void* d_ws, size_t ws_size,
                              hipStream_t stream) {
    const float* x_graph = (const float*)d_in[0];
    const int*   edge    = (const int*)d_in[1];
    const int*   row     = edge;
    const int*   col     = edge + N_EDGES;
    const float* x_state = (const float*)d_in[2];
    const float* h0      = (const float*)d_in[3];
    const float* c0      = (const float*)d_in[4];
    const float* W1      = (const float*)d_in[5];
    const float* b1      = (const float*)d_in[6];
    const float* W2      = (const float*)d_in[7];
    const float* b2      = (const float*)d_in[8];
    const float* W_ih    = (const float*)d_in[9];
    const float* W_hh    = (const float*)d_in[10];
    const float* b_ih    = (const float*)d_in[11];
    const float* b_hh    = (const float*)d_in[12];
    const float* W_fc    = (const float*)d_in[13];
    const float* b_fc    = (const float*)d_in[14];

    int*   gcur   = (int*)d_ws;                                  // 512
    uint*  staged = (uint*)(gcur + 512);                         // NRANGE*RCAP (7.2 MB)
    int*   cnt    = (int*)(staged + (size_t)NRANGE * RCAP);      // N
    int*   nbr    = cnt + N_NODES;                               // N*CAP (25.6 MB)
    uint*  hs8    = (uint*)(nbr + (size_t)N_NODES * CAP);        // N*8 (fp8 rows, 32B)
    uint*  hs2    = hs8 + (size_t)N_NODES * 8;                   // N*8
    float* pooled = (float*)(hs2 + (size_t)N_NODES * 8);         // 32
    float* gates  = pooled + C_HID;                              // 1024
    float* out    = (float*)d_out;

    int nb_g = (N_NODES + 63) / 64;                              // 1563

    hipMemsetAsync(gcur, 0, 512 * sizeof(int), stream);
    k_part <<<PBLK, 256, 0, stream>>>(row, col, gcur, staged, pooled);
    k_bgcn <<<NRANGE, 256, 0, stream>>>(gcur, staged, x_graph, W1, cnt, nbr, hs8);
    k_g1   <<<nb_g, 256, 0, stream>>>(hs8, cnt, nbr, b1, W2, hs2);
    k_g2   <<<nb_g, 256, 0, stream>>>(hs2, cnt, nbr, b2, pooled);
    k_gates<<<256, 256, 0, stream>>>(pooled, x_state, h0, W_ih, W_hh, b_ih, b_hh, gates);
    k_head <<<1, 256, 0, stream>>>(gates, c0, W_fc, b_fc, out);
}